// Round 15
// baseline (585.269 us; speedup 1.0000x reference)
//
#include <hip/hip_runtime.h>
#include <math.h>

#define D_DIM 1024     // hidden dim (K)
#define N_EXP 64       // experts (N)
#define BLK_ROWS 64    // rows per block
#define STRIDE 68      // LDS dword stride per row (64 + 4 pad, 16B-aligned)
#define NC 16          // iterations; each stages 64 rows x 64 cols (256B/row)
#define BSX (BLK_ROWS * STRIDE)
#define BSW (N_EXP * STRIDE)

// Round-11 lesson (measured): global coalescing is PER INSTRUCTION. Lanes 64B apart
// issuing 16B requests -> 4x fetch amplification (550 MB ~= 4 x 134 MB, exact).
// Writes amplify at >=256B granule (round 4: 4.19M 4B stores x 256B = 1073 MB, exact).
// Fix: every global load/store instruction is lane-contiguous:
//  - staging: wave wv, inst k, lane l -> row wv*16+k*4+(l>>4), 16B piece (l&15);
//    lanes 0-15 cover one row's 256B chunk contiguously (sectors fully packed).
//  - stores:  inst k, lane l -> wavebase + k*1024B + l*16B (1 KB contiguous/inst),
//    non-temporal (bypass L2, write-once data).
// LDS tile holds global cols [c*64,(c+1)*64) in natural order; GEMM core unchanged
// (lane q's K-partition becomes {c*64+q*16+t} -- still a partition, summed by shfl).

typedef float f32x4 __attribute__((ext_vector_type(4)));

__device__ __forceinline__ void top2_merge(float& m1, float& m2, float o1, float o2) {
    const float lo = fminf(m1, o1);
    m1 = fmaxf(m1, o1);
    m2 = fmaxf(lo, fmaxf(m2, o2));
}

__global__ __launch_bounds__(256, 2)
void spiking_router_kernel(const float* __restrict__ x,
                           const float* __restrict__ Wt,
                           const float* __restrict__ bias,
                           float* __restrict__ out,
                           int m_rows)
{
    __shared__ __align__(16) float xs[2][BSX];   // xs[0] reused as logit tile in epilogue
    __shared__ __align__(16) float ws[2][BSW];
    __shared__ float b_s[N_EXP];
    __shared__ float2 tops[BLK_ROWS][2];   // per-row (m1,m2) per expert-half

    const int tid  = threadIdx.x;
    const int blk  = blockIdx.x;
    const int lane   = tid & 63;
    const int wv     = tid >> 6;
    // compute mapping (unchanged)
    const int i      = lane & 3;         // row-lane
    const int j      = (lane >> 2) & 3;  // expert-lane
    const int q      = lane >> 4;        // K-quarter
    const int wave_r = wv >> 1;          // row half (32 rows)
    const int wave_c = wv & 1;           // expert half (32 experts)
    // staging mapping: per inst k, this lane's row offset and 16B piece
    const int prow = wv * 16 + (lane >> 4);   // +k*4 per inst
    const int pcol = (lane & 15) * 4;         // dwords within the 64-col chunk

    if (tid < N_EXP) b_s[tid] = bias[tid];

    const long row0 = (long)blk * BLK_ROWS;

    const float* gxk[4];
    const float* gwk[4];
    #pragma unroll
    for (int k = 0; k < 4; ++k) {
        gxk[k] = x  + (row0 + prow + k * 4) * D_DIM + pcol;
        gwk[k] = Wt + (long)(prow + k * 4) * D_DIM + pcol;
    }

    f32x4 px[4], pw[4];

    // ---- prologue: load chunk 0 (cols [0,64)) into buffer 0 ----
    #pragma unroll
    for (int k = 0; k < 4; ++k) {
        px[k] = *(const f32x4*)gxk[k];
        pw[k] = *(const f32x4*)gwk[k];
    }
    #pragma unroll
    for (int k = 0; k < 4; ++k) {
        *(f32x4*)&xs[0][(prow + k * 4) * STRIDE + pcol] = px[k];
        *(f32x4*)&ws[0][(prow + k * 4) * STRIDE + pcol] = pw[k];
    }

    float acc[64];
    #pragma unroll
    for (int t = 0; t < 64; ++t) acc[t] = 0.0f;

    // per-row / per-expert LDS dword offsets within a buffer (unchanged)
    int xoff[8], woff[8];
    #pragma unroll
    for (int rr = 0; rr < 8; ++rr) xoff[rr] = (wave_r * 32 + rr * 4 + i) * STRIDE + q * 16;
    #pragma unroll
    for (int ee = 0; ee < 8; ++ee) woff[ee] = (wave_c * 32 + ee * 4 + j) * STRIDE + q * 16;

    // ---- main loop: one barrier/iter, LDS double-buffered, reg prefetch ----
    for (int c = 0; c < NC; ++c) {
        __syncthreads();
        const bool more = (c + 1 < NC);
        if (more) {
            #pragma unroll
            for (int k = 0; k < 4; ++k) {
                px[k] = *(const f32x4*)(gxk[k] + (c + 1) * 64);
                pw[k] = *(const f32x4*)(gwk[k] + (c + 1) * 64);
            }
        }
        const float* xb = xs[c & 1];
        const float* wb = ws[c & 1];
        #pragma unroll
        for (int c4 = 0; c4 < 4; ++c4) {
            float4 a[8], w[8];
            #pragma unroll
            for (int rr = 0; rr < 8; ++rr)
                a[rr] = *(const float4*)&xb[xoff[rr] + c4 * 4];
            #pragma unroll
            for (int ee = 0; ee < 8; ++ee)
                w[ee] = *(const float4*)&wb[woff[ee] + c4 * 4];
            // k-outer: same-acc fmas are 64 apart -> no dep-latency stalls
            #pragma unroll
            for (int k = 0; k < 4; ++k) {
                #pragma unroll
                for (int ee = 0; ee < 8; ++ee) {
                    const float wk = (k == 0) ? w[ee].x : (k == 1) ? w[ee].y
                                   : (k == 2) ? w[ee].z : w[ee].w;
                    #pragma unroll
                    for (int rr = 0; rr < 8; ++rr) {
                        const float ak = (k == 0) ? a[rr].x : (k == 1) ? a[rr].y
                                       : (k == 2) ? a[rr].z : a[rr].w;
                        acc[rr * 8 + ee] = fmaf(ak, wk, acc[rr * 8 + ee]);
                    }
                }
            }
        }
        if (more) {
            const int nb = (c + 1) & 1;
            #pragma unroll
            for (int k = 0; k < 4; ++k) {
                *(f32x4*)&xs[nb][(prow + k * 4) * STRIDE + pcol] = px[k];
                *(f32x4*)&ws[nb][(prow + k * 4) * STRIDE + pcol] = pw[k];
            }
        }
    }

    // ---- K-quarter all-reduce (lanes l, l^16, l^32, l^48 share a tile) + bias ----
    #pragma unroll
    for (int t = 0; t < 64; ++t) {
        float v = acc[t];
        v += __shfl_xor(v, 16, 64);
        v += __shfl_xor(v, 32, 64);
        acc[t] = v;
    }
    #pragma unroll
    for (int ee = 0; ee < 8; ++ee) {
        const float be = b_s[wave_c * 32 + ee * 4 + j];
        #pragma unroll
        for (int rr = 0; rr < 8; ++rr) acc[rr * 8 + ee] += be;
    }

    // ---- per-row local top-2 over this lane's 8 experts (branchless med3) ----
    float t1[8], t2[8];
    #pragma unroll
    for (int rr = 0; rr < 8; ++rr) {
        float m1 = -INFINITY, m2 = -INFINITY;
        #pragma unroll
        for (int ee = 0; ee < 8; ++ee) {
            const float v = acc[rr * 8 + ee];
            m2 = __builtin_amdgcn_fmed3f(m2, v, m1);
            m1 = fmaxf(m1, v);
        }
        t1[rr] = m1; t2[rr] = m2;
    }
    // merge across the 4 expert-lanes (lane^4, lane^8); result uniform over j and q
    #pragma unroll
    for (int rr = 0; rr < 8; ++rr) {
        float o1 = __shfl_xor(t1[rr], 4, 64);
        float o2 = __shfl_xor(t2[rr], 4, 64);
        top2_merge(t1[rr], t2[rr], o1, o2);
        o1 = __shfl_xor(t1[rr], 8, 64);
        o2 = __shfl_xor(t2[rr], 8, 64);
        top2_merge(t1[rr], t2[rr], o1, o2);
    }

    // ---- epilogue stage 1: scatter logits into LDS tile (xs[0] free: last iter
    // reads only xs[1]; all waves passed the c=15 barrier) ----
    float* const lg_tile = &xs[0][0];   // [BLK_ROWS][STRIDE]
    if (q == 0) {
        #pragma unroll
        for (int rr = 0; rr < 8; ++rr) {
            const int row = wave_r * 32 + rr * 4 + i;
            #pragma unroll
            for (int ee = 0; ee < 8; ++ee)   // banks 4i+j: conflict-free
                lg_tile[row * STRIDE + wave_c * 32 + ee * 4 + j] = acc[rr * 8 + ee];
        }
        if (j == 0) {
            #pragma unroll
            for (int rr = 0; rr < 8; ++rr)
                tops[wave_r * 32 + rr * 4 + i][wave_c] = make_float2(t1[rr], t2[rr]);
        }
    }
    __syncthreads();

    // ---- epilogue stage 2: readout + quantize + NT stores, 1 KB contiguous/inst ----
    // inst k, lane l -> row16 = wv*16 + k*4 + (l>>4), piece l&15;
    // dst dword = (row0+wv*16)*64 + k*256 + l*4 (lane-consecutive for fixed k).
    float* const po_base = out + (row0 + wv * 16) * N_EXP;
    float* const pl_base = out + (long)m_rows * N_EXP + (row0 + wv * 16) * N_EXP;
    #pragma unroll
    for (int k = 0; k < 4; ++k) {
        const int row16 = wv * 16 + k * 4 + (lane >> 4);
        const float2 ta = tops[row16][0];   // 16-lane broadcast reads
        const float2 tb = tops[row16][1];
        float u1 = ta.x, u2 = ta.y;
        top2_merge(u1, u2, tb.x, tb.y);
        const float th = u2;                // 2nd max of union = top-2 threshold
        const f32x4 lg = *(const f32x4*)&lg_tile[row16 * STRIDE + (lane & 15) * 4];
        f32x4 rw;
        rw.x = (lg.x >= th) ? fminf(floorf(fmaxf(lg.x, 0.0f)), 4.0f) : 0.0f;
        rw.y = (lg.y >= th) ? fminf(floorf(fmaxf(lg.y, 0.0f)), 4.0f) : 0.0f;
        rw.z = (lg.z >= th) ? fminf(floorf(fmaxf(lg.z, 0.0f)), 4.0f) : 0.0f;
        rw.w = (lg.w >= th) ? fminf(floorf(fmaxf(lg.w, 0.0f)), 4.0f) : 0.0f;
        __builtin_nontemporal_store(rw, (f32x4*)(po_base + k * 256 + lane * 4));
        __builtin_nontemporal_store(lg, (f32x4*)(pl_base + k * 256 + lane * 4));
    }
}

extern "C" void kernel_launch(void* const* d_in, const int* in_sizes, int n_in,
                              void* d_out, int out_size, void* d_ws, size_t ws_size,
                              hipStream_t stream)
{
    const float* x  = (const float*)d_in[0];
    const float* Wt = (const float*)d_in[1];
    const float* b  = (const float*)d_in[2];
    float* out = (float*)d_out;
    const int m_rows = in_sizes[0] / D_DIM;   // 8*4096 = 32768
    const int grid = m_rows / BLK_ROWS;       // 512
    spiking_router_kernel<<<grid, 256, 0, stream>>>(x, Wt, b, out, m_rows);
}